// Round 6
// baseline (133.826 us; speedup 1.0000x reference)
//
#include <hip/hip_runtime.h>
#include <hip/hip_bf16.h>

// Problem constants (GPT2Attention classic): B=2, S=2048, E=1024, H=16, HD=64
#define B_ 2
#define S_ 2048
#define E_ 1024
#define H_ 16
#define HD_ 64
#define T_ (B_ * S_)  // 4096 tokens

typedef short bf16x8 __attribute__((ext_vector_type(8)));
typedef short bf16x4 __attribute__((ext_vector_type(4)));
typedef float f32x4 __attribute__((ext_vector_type(4)));

__device__ __forceinline__ short f2bf(float f) {
  union { float f; unsigned u; } v;
  v.f = f;
  unsigned r = v.u + 0x7fffu + ((v.u >> 16) & 1u);
  return (short)(r >> 16);
}

// async global -> LDS, 16 B per lane; LDS dest = wave-uniform base + lane*16
__device__ __forceinline__ void gll16(const void* g, void* l) {
  __builtin_amdgcn_global_load_lds(
      (const __attribute__((address_space(1))) unsigned int*)g,
      (__attribute__((address_space(3))) unsigned int*)l, 16, 0, 0);
}

// KV blob: per (bh, 64-key tile) 8192 shorts = 16 KB, in MFMA fragment order.
//   K frags: g = nb*2+half (g in [0,8)):  blob[g*512 + lane*8 + j]
//            = K[k0 + nb*16 + (lane&15)][half*32 + (lane>>4)*8 + j]
//   V frags: g = p2*4+db:                 blob[4096 + g*512 + lane*8 + j]
//            = V[k0 + (2*p2 + (j>>2))*16 + (lane>>4)*4 + (j&3)][db*16 + (lane&15)]
// Blob staging is an IDENTITY copy -> global_load_lds compatible (no padding).

// ---------------------------------------------------------------- kernel 1+2
// Merged: bid < 512 -> QKV projection; bid >= 512 -> proj_w fp32->bf16 convert.
// Q pre-scaled by 0.125*log2(e) (exp2 domain). Q -> [B,H,S,HD]; K,V -> blob.
__global__ __launch_bounds__(256) void qkv_conv_kernel(
    const float* __restrict__ x,
    const float* __restrict__ wq, const float* __restrict__ bq,
    const float* __restrict__ wk, const float* __restrict__ bk,
    const float* __restrict__ wv, const float* __restrict__ bv,
    short* __restrict__ Q, short* __restrict__ KV,
    const float* __restrict__ pw, short* __restrict__ pwb) {
  const int tid = threadIdx.x;
  if (blockIdx.x >= 512) {
    int i = ((blockIdx.x - 512) * 256 + tid) * 4;
    float4 f = *(const float4*)(pw + i);
    bf16x4 o;
    o[0] = f2bf(f.x); o[1] = f2bf(f.y); o[2] = f2bf(f.z); o[3] = f2bf(f.w);
    *(bf16x4*)(pwb + i) = o;
    return;
  }
  __shared__ short Xs[64][136];   // 64 tokens x 128 cols (2 heads)
  __shared__ short Ws[192][72];   // Wq|Wk|Wv rows
  __shared__ short Qt[64][68], Kt[64][68], Vt[64][68];

  const int bid = blockIdx.x;
  const int tb = bid >> 3, hg = bid & 7;   // token block, head group (2 heads)
  const int s0 = (tb * 64) & (S_ - 1);
  const int kt = s0 >> 6;                  // this token block's key-tile index
  const int bb = (tb * 64) >> 11;          // batch index
  const int wave = tid >> 6, lane = tid & 63;
  const int lrow = lane & 15, quad = lane >> 4;

#pragma unroll
  for (int i = 0; i < 8; i++) {
    int c = tid + 256 * i;
    int row = c >> 5, col4 = c & 31;
    float4 f = *(const float4*)(x + ((long)(tb * 64 + row)) * E_ + hg * 128 + col4 * 4);
    bf16x4 o;
    o[0] = f2bf(f.x); o[1] = f2bf(f.y); o[2] = f2bf(f.z); o[3] = f2bf(f.w);
    *(bf16x4*)&Xs[row][col4 * 4] = o;
  }
#pragma unroll
  for (int m = 0; m < 3; m++) {
    const float* w = (m == 0) ? wq : (m == 1) ? wk : wv;
#pragma unroll
    for (int i = 0; i < 4; i++) {
      int c = tid + 256 * i;
      int row = m * 64 + (c >> 4), col = (c & 15) * 4;
      float4 f = *(const float4*)(w + (long)c * 4);
      bf16x4 o;
      o[0] = f2bf(f.x); o[1] = f2bf(f.y); o[2] = f2bf(f.z); o[3] = f2bf(f.w);
      *(bf16x4*)&Ws[row][col] = o;
    }
  }
  float bias[12];
#pragma unroll
  for (int nb = 0; nb < 12; nb++) {
    int sel = nb >> 2;
    int e = ((nb & 3) * 16) + lrow;
    bias[nb] = ((sel == 0) ? bq : (sel == 1) ? bk : bv)[e];
  }
  __syncthreads();

  bf16x8 bf0[12], bf1[12];
#pragma unroll
  for (int nb = 0; nb < 12; nb++) {
    bf0[nb] = *(bf16x8*)&Ws[nb * 16 + lrow][quad * 8];
    bf1[nb] = *(bf16x8*)&Ws[nb * 16 + lrow][32 + quad * 8];
  }

  const float QSCALE = 0.125f * 1.44269504089f;  // 1/sqrt(64) * log2(e)
  for (int hl = 0; hl < 2; hl++) {
    const int h = hg * 2 + hl;
    bf16x8 a0 = *(bf16x8*)&Xs[wave * 16 + lrow][hl * 64 + quad * 8];
    bf16x8 a1 = *(bf16x8*)&Xs[wave * 16 + lrow][hl * 64 + 32 + quad * 8];
#pragma unroll
    for (int nb = 0; nb < 12; nb++) {
      f32x4 acc = {0.f, 0.f, 0.f, 0.f};
      acc = __builtin_amdgcn_mfma_f32_16x16x32_bf16(a0, bf0[nb], acc, 0, 0, 0);
      acc = __builtin_amdgcn_mfma_f32_16x16x32_bf16(a1, bf1[nb], acc, 0, 0, 0);
      const int sel = nb >> 2;
      const float scale = (sel == 0) ? QSCALE : 1.0f;
      short (*ct)[68] = (sel == 0) ? Qt : (sel == 1) ? Kt : Vt;
#pragma unroll
      for (int r = 0; r < 4; r++) {
        ct[wave * 16 + quad * 4 + r][(nb & 3) * 16 + lrow] =
            f2bf((acc[r] + bias[nb]) * scale);
      }
    }
    __syncthreads();

    const int bh = bb * H_ + h;
    short* Qg = Q + ((long)bh * S_ + s0) * HD_;
    short* Tg = KV + ((long)(bh * 32 + kt)) * 8192;
#pragma unroll
    for (int i = 0; i < 2; i++) {
      int c = tid + 256 * i;
      int row = c >> 3, col = (c & 7) * 8;
      *(bf16x8*)(Qg + (long)row * HD_ + col) = *(bf16x8*)&Qt[row][col];
    }
#pragma unroll
    for (int u = 0; u < 4; u++) {
      int fid = tid + 256 * u;
      bf16x8 val;
      int lane2 = fid & 63;
      int quad2 = lane2 >> 4, lrow2 = lane2 & 15;
      if (u < 2) {  // K chunk
        int g = fid >> 6;
        int nb = g >> 1, half = g & 1;
        val = *(bf16x8*)&Kt[nb * 16 + lrow2][half * 32 + quad2 * 8];
      } else {      // V chunk (transpose gather)
        int g = (fid >> 6) & 7;
        int p2 = g >> 2, db = g & 3;
#pragma unroll
        for (int j = 0; j < 8; j++) {
          int key = (2 * p2 + (j >> 2)) * 16 + quad2 * 4 + (j & 3);
          val[j] = Vt[key][db * 16 + lrow2];
        }
      }
      *(bf16x8*)(Tg + fid * 8) = val;
    }
    __syncthreads();
  }
}

// ---------------------------------------------------------------- kernel 3
// Flash attention, causal, no-max (bounded scores), exp2-domain Q.
// Uniform-work decomposition: block `a` (0..15) owns strips A = a (tiles
// 0..a) and B = 31-a (tiles 0..31-a); 33 substrip-tiles per block, uniform.
// MERGED-PHASE super-tile processing (latency-bound fix; raw counters show
// all pipes at 25-35% with 8 waves/CU): the two 64-key tiles of a staged
// 32 KB super are processed as wide phases -- {kf+QK both} -> {vf issue +
// mask + exp/pack both} -> {PV both} -- so within one wave 16 ds_read_b128
// are in flight together, the 128-exp TRANS cluster of tile0/tile1 overlaps
// PV MFMA issue, and MFMA clusters are 32 wide (T15 mechanism as a pure
// reorder). Per-row FP order preserved (t0 before t1 everywhere) -> output
// bitwise identical. VGPR ~200 is free at (256,2); occupancy is LDS-capped.
__global__ __launch_bounds__(256, 2) void attn_kernel(
    const short* __restrict__ Q, const short* __restrict__ KV,
    short* __restrict__ O /* [T][E] bf16 */) {
  __shared__ __align__(16) short L[2][16384];  // [buf][tile0 K|V, tile1 K|V]

  const int tid = threadIdx.x;
  const int bid = blockIdx.x;      // 512 = 16 a * 32 bh
  const int bh = bid & 31;
  const int a = bid >> 5;          // 0..15; uniform 33 units of work
  const int b = bh >> 4, h = bh & 15;
  const long qbase = ((long)bh) << 17;  // bh * S*HD

  const int wave = tid >> 6, lane = tid & 63;
  const int lrow = lane & 15, quad = lane >> 4;
  const int qgA = a * 64 + wave * 16 + lrow;          // substrip A row
  const int qgB = (31 - a) * 64 + wave * 16 + lrow;   // substrip B row
  const int tmax = 31 - a;                            // last key-tile (B diag)

  const short* qpA = Q + qbase + (long)qgA * HD_;
  const short* qpB = Q + qbase + (long)qgB * HD_;
  bf16x8 qfA0 = *(const bf16x8*)(qpA + quad * 8);
  bf16x8 qfA1 = *(const bf16x8*)(qpA + 32 + quad * 8);
  bf16x8 qfB0 = *(const bf16x8*)(qpB + quad * 8);
  bf16x8 qfB1 = *(const bf16x8*)(qpB + 32 + quad * 8);

  const char* Tg = (const char*)(KV + ((long)bh * 32) * 8192);

  // async stage one 32 KB super-tile; wave covers chunks u*4+wave (1 KB each)
  auto STAGE = [&](int sup, int buf) {
    const char* gt = Tg + (long)sup * 32768;
#pragma unroll
    for (int u = 0; u < 8; u++) {
      const int chunk = u * 4 + wave;
      gll16(gt + chunk * 1024 + lane * 16, &L[buf][chunk * 512]);
    }
  };

  // exp2 + lsum + truncate-pack one 4-fragment score set into 2 bf16x8 P^T
  // fragments whose slot->key order matches vf's (j<4: keys 32p2+quad*4+j,
  // j>=4: +16).
  auto EXPPACK = [&](f32x4* sc, bf16x8* pf, float& ls) {
#pragma unroll
    for (int p2 = 0; p2 < 2; p2++) {
      unsigned ub[8];
#pragma unroll
      for (int nb2 = 0; nb2 < 2; nb2++) {
#pragma unroll
        for (int r = 0; r < 4; r++) {
          float p = __builtin_amdgcn_exp2f(sc[2 * p2 + nb2][r]);
          ls += p;
          ub[nb2 * 4 + r] = __float_as_uint(p);
        }
      }
      union { unsigned q[4]; bf16x8 v; } pk;
      pk.q[0] = __builtin_amdgcn_perm(ub[1], ub[0], 0x07060302u);
      pk.q[1] = __builtin_amdgcn_perm(ub[3], ub[2], 0x07060302u);
      pk.q[2] = __builtin_amdgcn_perm(ub[5], ub[4], 0x07060302u);
      pk.q[3] = __builtin_amdgcn_perm(ub[7], ub[6], 0x07060302u);
      pf[p2] = pk.v;
    }
  };

  f32x4 OA[4], OB[4];
#pragma unroll
  for (int db = 0; db < 4; db++) {
    OA[db] = f32x4{0.f, 0.f, 0.f, 0.f};
    OB[db] = f32x4{0.f, 0.f, 0.f, 0.f};
  }
  float lsA = 0.f, lsB = 0.f;

  const int nsup = (33 - a) >> 1;  // supers cover tiles 0..tmax (+1 dead if a odd)
  STAGE(0, 0);
  for (int it = 0; it < nsup; it++) {
    const int buf = it & 1;
    __syncthreads();  // vmcnt drain: staging of buf complete; buf^1 free
    if (it + 1 < nsup) STAGE(it + 1, buf ^ 1);

    const int t0 = 2 * it, t1 = t0 + 1;
    const short* Lb0 = &L[buf][0];
    const short* Lb1 = &L[buf][8192];
    const bool live1 = (t1 <= tmax);          // dead half-super when a odd
    const bool doA0 = (t0 <= a);
    const bool doA1 = live1 && (t1 <= a);

    // ---- Phase 1: K fragments + QK^T for BOTH tiles (32-wide MFMA cluster)
    bf16x8 kf0[8], kf1[8];
#pragma unroll
    for (int g2 = 0; g2 < 8; g2++)
      kf0[g2] = *(bf16x8*)&Lb0[g2 * 512 + lane * 8];
    if (live1) {
#pragma unroll
      for (int g2 = 0; g2 < 8; g2++)
        kf1[g2] = *(bf16x8*)&Lb1[g2 * 512 + lane * 8];
    }

    f32x4 scA0[4], scB0[4], scA1[4], scB1[4];
    __builtin_amdgcn_s_setprio(1);
#pragma unroll
    for (int nb = 0; nb < 4; nb++) {
      f32x4 cb = {0.f, 0.f, 0.f, 0.f};
      cb = __builtin_amdgcn_mfma_f32_16x16x32_bf16(kf0[2 * nb], qfB0, cb, 0, 0, 0);
      cb = __builtin_amdgcn_mfma_f32_16x16x32_bf16(kf0[2 * nb + 1], qfB1, cb, 0, 0, 0);
      scB0[nb] = cb;
    }
    if (doA0) {
#pragma unroll
      for (int nb = 0; nb < 4; nb++) {
        f32x4 ca = {0.f, 0.f, 0.f, 0.f};
        ca = __builtin_amdgcn_mfma_f32_16x16x32_bf16(kf0[2 * nb], qfA0, ca, 0, 0, 0);
        ca = __builtin_amdgcn_mfma_f32_16x16x32_bf16(kf0[2 * nb + 1], qfA1, ca, 0, 0, 0);
        scA0[nb] = ca;
      }
    }
    if (live1) {
#pragma unroll
      for (int nb = 0; nb < 4; nb++) {
        f32x4 cb = {0.f, 0.f, 0.f, 0.f};
        cb = __builtin_amdgcn_mfma_f32_16x16x32_bf16(kf1[2 * nb], qfB0, cb, 0, 0, 0);
        cb = __builtin_amdgcn_mfma_f32_16x16x32_bf16(kf1[2 * nb + 1], qfB1, cb, 0, 0, 0);
        scB1[nb] = cb;
      }
      if (doA1) {
#pragma unroll
        for (int nb = 0; nb < 4; nb++) {
          f32x4 ca = {0.f, 0.f, 0.f, 0.f};
          ca = __builtin_amdgcn_mfma_f32_16x16x32_bf16(kf1[2 * nb], qfA0, ca, 0, 0, 0);
          ca = __builtin_amdgcn_mfma_f32_16x16x32_bf16(kf1[2 * nb + 1], qfA1, ca, 0, 0, 0);
          scA1[nb] = ca;
        }
      }
    }
    __builtin_amdgcn_s_setprio(0);

    // ---- Phase 2: V fragments issued for both tiles; masks; exp/pack
    bf16x8 vf0[8], vf1[8];
#pragma unroll
    for (int g2 = 0; g2 < 8; g2++)
      vf0[g2] = *(bf16x8*)&Lb0[4096 + g2 * 512 + lane * 8];
    if (live1) {
#pragma unroll
      for (int g2 = 0; g2 < 8; g2++)
        vf1[g2] = *(bf16x8*)&Lb1[4096 + g2 * 512 + lane * 8];
    }

    // causal masks (A diagonal at t==a; B diagonal at t==tmax)
    if (t0 == a) {
#pragma unroll
      for (int nb = 0; nb < 4; nb++) {
        int kgl = t0 * 64 + nb * 16 + quad * 4;
#pragma unroll
        for (int r = 0; r < 4; r++)
          if (kgl + r > qgA) scA0[nb][r] = -1e30f;
      }
    }
    if (t0 == tmax) {
#pragma unroll
      for (int nb = 0; nb < 4; nb++) {
        int kgl = t0 * 64 + nb * 16 + quad * 4;
#pragma unroll
        for (int r = 0; r < 4; r++)
          if (kgl + r > qgB) scB0[nb][r] = -1e30f;
      }
    }
    if (live1 && t1 == a) {
#pragma unroll
      for (int nb = 0; nb < 4; nb++) {
        int kgl = t1 * 64 + nb * 16 + quad * 4;
#pragma unroll
        for (int r = 0; r < 4; r++)
          if (kgl + r > qgA) scA1[nb][r] = -1e30f;
      }
    }
    if (live1 && t1 == tmax) {
#pragma unroll
      for (int nb = 0; nb < 4; nb++) {
        int kgl = t1 * 64 + nb * 16 + quad * 4;
#pragma unroll
        for (int r = 0; r < 4; r++)
          if (kgl + r > qgB) scB1[nb][r] = -1e30f;
      }
    }

    // exp/pack, t0 before t1 (lsum accumulation order preserved)
    bf16x8 pfA0[2], pfB0[2], pfA1[2], pfB1[2];
    EXPPACK(scB0, pfB0, lsB);
    if (doA0) EXPPACK(scA0, pfA0, lsA);
    if (live1) {
      EXPPACK(scB1, pfB1, lsB);
      if (doA1) EXPPACK(scA1, pfA1, lsA);
    }

    // ---- Phase 3: O^T += V^T . P^T for both tiles (32-wide MFMA cluster)
    __builtin_amdgcn_s_setprio(1);
#pragma unroll
    for (int p2 = 0; p2 < 2; p2++) {
#pragma unroll
      for (int db = 0; db < 4; db++) {
        bf16x8 vv = vf0[p2 * 4 + db];
        OB[db] = __builtin_amdgcn_mfma_f32_16x16x32_bf16(vv, pfB0[p2], OB[db], 0, 0, 0);
        if (doA0) {
          OA[db] = __builtin_amdgcn_mfma_f32_16x16x32_bf16(vv, pfA0[p2], OA[db], 0, 0, 0);
        }
      }
    }
    if (live1) {
#pragma unroll
      for (int p2 = 0; p2 < 2; p2++) {
#pragma unroll
        for (int db = 0; db < 4; db++) {
          bf16x8 vv = vf1[p2 * 4 + db];
          OB[db] = __builtin_amdgcn_mfma_f32_16x16x32_bf16(vv, pfB1[p2], OB[db], 0, 0, 0);
          if (doA1) {
            OA[db] = __builtin_amdgcn_mfma_f32_16x16x32_bf16(vv, pfA1[p2], OA[db], 0, 0, 0);
          }
        }
      }
    }
    __builtin_amdgcn_s_setprio(0);
  }

  // epilogue: reduce l across quads, scale, store both substrips
  lsA += __shfl_xor(lsA, 16);
  lsA += __shfl_xor(lsA, 32);
  lsB += __shfl_xor(lsB, 16);
  lsB += __shfl_xor(lsB, 32);
  const float invA = 1.f / lsA, invB = 1.f / lsB;
  short* oA = O + ((long)b * S_ + qgA) * E_ + h * HD_;
  short* oB = O + ((long)b * S_ + qgB) * E_ + h * HD_;
#pragma unroll
  for (int db = 0; db < 4; db++) {
    bf16x4 oa, ob;
#pragma unroll
    for (int r = 0; r < 4; r++) {
      oa[r] = f2bf(OA[db][r] * invA);
      ob[r] = f2bf(OB[db][r] * invB);
    }
    *(bf16x4*)(oA + db * 16 + quad * 4) = oa;
    *(bf16x4*)(oB + db * 16 + quad * 4) = ob;
  }
}

// ---------------------------------------------------------------- kernel 4
// out = attn(4096x1024 bf16) . proj_w^T + proj_b  -> fp32
// 128x64 tile (M x N), BK=64, grid 512 (2 blocks/CU).
// m97 structure: async global_load_lds (width 16) into LINEAR double-buffered
// LDS, ONE barrier per 64-deep K-step. XOR-swizzle (c^(row&7)) applied to the
// per-lane global source and the LDS read (T2/m173 pattern).
__global__ __launch_bounds__(256) void proj_kernel(
    const short* __restrict__ A, const short* __restrict__ W,
    const float* __restrict__ bias, float* __restrict__ out) {
  __shared__ __align__(16) short As[2][128][64];  // 2 x 16 KB
  __shared__ __align__(16) short Bs[2][64][64];   // 2 x  8 KB
  const int tid = threadIdx.x;
  const int bid = blockIdx.x;  // 512 = 32 (M/128) * 16 (N/64)
  const int m0 = (bid >> 4) * 128;
  const int n0 = (bid & 15) * 64;
  const int wave = tid >> 6, lane = tid & 63;
  const int wm = wave >> 1, wn = wave & 1;
  const int lrow = lane & 15, quad = lane >> 4;

  // stage one K-step: A tile 128x64 (1024 chunks), W tile 64x64 (512 chunks)
  auto STAGE = [&](int k0, int bufi) {
#pragma unroll
    for (int u = 0; u < 4; u++) {
      int d = u * 256 + tid;           // dest chunk (lane-linear)
      int row = d >> 3, c = d & 7;
      gll16(A + (long)(m0 + row) * E_ + k0 + ((c ^ (row & 7)) * 8),
            (short*)As[bufi] + (u * 256 + wave * 64) * 8);
    }
#pragma unroll
    for (int u = 0; u < 2; u++) {
      int d = u * 256 + tid;
      int row = d >> 3, c = d & 7;
      gll16(W + (long)(n0 + row) * E_ + k0 + ((c ^ (row & 7)) * 8),
            (short*)Bs[bufi] + (u * 256 + wave * 64) * 8);
    }
  };

  f32x4 acc[4][2];
#pragma unroll
  for (int i = 0; i < 4; i++)
#pragma unroll
    for (int j = 0; j < 2; j++) acc[i][j] = f32x4{0.f, 0.f, 0.f, 0.f};

  STAGE(0, 0);
  for (int kk = 0; kk < 16; kk++) {
    const int buf = kk & 1;
    __syncthreads();  // staging of buf landed; all reads of buf^1 done
    if (kk < 15) STAGE((kk + 1) * 64, buf ^ 1);

#pragma unroll
    for (int kh = 0; kh < 2; kh++) {
      bf16x8 af[4], bfr[2];
#pragma unroll
      for (int i = 0; i < 4; i++) {
        int ra = wm * 64 + i * 16 + lrow;
        af[i] = *(bf16x8*)&As[buf][ra][((kh * 4 + quad) ^ (lrow & 7)) * 8];
      }
#pragma unroll
      for (int j = 0; j < 2; j++) {
        int rb = wn * 32 + j * 16 + lrow;
        bfr[j] = *(bf16x8*)&Bs[buf][rb][((kh * 4 + quad) ^ (lrow & 7)) * 8];
      }
#pragma unroll
      for (int i = 0; i < 4; i++)
#pragma unroll
        for (int j = 0; j < 2; j++)
          acc[i][j] = __builtin_amdgcn_mfma_f32_16x16x32_bf16(af[i], bfr[j], acc[i][j], 0, 0, 0);
    }
  }

#pragma unroll
  for (int j = 0; j < 2; j++) {
    int col = n0 + wn * 32 + j * 16 + lrow;
    float bv = bias[col];
#pragma unroll
    for (int i = 0; i < 4; i++) {
#pragma unroll
      for (int r = 0; r < 4; r++) {
        int row = m0 + wm * 64 + i * 16 + quad * 4 + r;
        out[(long)row * E_ + col] = acc[i][j][r] + bv;
      }
    }
  }
}

// ---------------------------------------------------------------- launch
extern "C" void kernel_launch(void* const* d_in, const int* in_sizes, int n_in,
                              void* d_out, int out_size, void* d_ws, size_t ws_size,
                              hipStream_t stream) {
  const float* x  = (const float*)d_in[0];
  const float* wq = (const float*)d_in[1];
  const float* bq = (const float*)d_in[2];
  const float* wk = (const float*)d_in[3];
  const float* bk = (const float*)d_in[4];
  const float* wv = (const float*)d_in[5];
  const float* bv = (const float*)d_in[6];
  const float* pw = (const float*)d_in[7];
  const float* pb = (const float*)d_in[8];
  float* out = (float*)d_out;

  char* ws = (char*)d_ws;
  short* Qb = (short*)(ws);                                   // 8 MB
  short* KVb = (short*)(ws + (size_t)8 * 1024 * 1024);        // 16 MB blob
  short* AO = (short*)(ws + (size_t)24 * 1024 * 1024);        // [T][E] bf16, 8 MB
  short* PW = (short*)(ws + (size_t)32 * 1024 * 1024);        // 2 MB

  qkv_conv_kernel<<<dim3(512 + 1024), dim3(256), 0, stream>>>(
      x, wq, bq, wk, bk, wv, bv, Qb, KVb, pw, PW);
  attn_kernel<<<dim3(16 * 32), dim3(256), 0, stream>>>(Qb, KVb, AO);
  proj_kernel<<<dim3(32 * 16), dim3(256), 0, stream>>>(AO, PW, pb, out);
}

// Round 8
// 132.041 us; speedup vs baseline: 1.0135x; 1.0135x over previous
//
#include <hip/hip_runtime.h>
#include <hip/hip_bf16.h>

// Problem constants (GPT2Attention classic): B=2, S=2048, E=1024, H=16, HD=64
#define B_ 2
#define S_ 2048
#define E_ 1024
#define H_ 16
#define HD_ 64
#define T_ (B_ * S_)  // 4096 tokens

typedef short bf16x8 __attribute__((ext_vector_type(8)));
typedef short bf16x4 __attribute__((ext_vector_type(4)));
typedef float f32x4 __attribute__((ext_vector_type(4)));

__device__ __forceinline__ short f2bf(float f) {
  union { float f; unsigned u; } v;
  v.f = f;
  unsigned r = v.u + 0x7fffu + ((v.u >> 16) & 1u);
  return (short)(r >> 16);
}

// async global -> LDS, 16 B per lane; LDS dest = wave-uniform base + lane*16
__device__ __forceinline__ void gll16(const void* g, void* l) {
  __builtin_amdgcn_global_load_lds(
      (const __attribute__((address_space(1))) unsigned int*)g,
      (__attribute__((address_space(3))) unsigned int*)l, 16, 0, 0);
}

// KV blob: per (bh, 64-key tile) 8192 shorts = 16 KB, in MFMA fragment order.
//   K frags: g = nb*2+half (g in [0,8)):  blob[g*512 + lane*8 + j]
//            = K[k0 + nb*16 + (lane&15)][half*32 + (lane>>4)*8 + j]
//   V frags: g = p2*4+db:                 blob[4096 + g*512 + lane*8 + j]
//            = V[k0 + (2*p2 + (j>>2))*16 + (lane>>4)*4 + (j&3)][db*16 + (lane&15)]
// Blob staging is an IDENTITY copy -> global_load_lds compatible (no padding).
//
// NOTE (Round 7): single-kernel fusion via hipLaunchCooperativeKernel FAILED
// correctness (absmax 3.7): cross-XCD per-L2 non-coherence — grid.sync() does
// not write-back/invalidate L2 for plain stores on gfx950/ROCm7.2 (guide G16).
// Split kernels are the correct structure here; kernel boundaries provide the
// required device-level coherence.

// ---------------------------------------------------------------- kernel 1+2
// Merged: bid < 512 -> QKV projection; bid >= 512 -> proj_w fp32->bf16 convert.
// Q pre-scaled by 0.125*log2(e) (exp2 domain). Q -> [B,H,S,HD]; K,V -> blob.
__global__ __launch_bounds__(256) void qkv_conv_kernel(
    const float* __restrict__ x,
    const float* __restrict__ wq, const float* __restrict__ bq,
    const float* __restrict__ wk, const float* __restrict__ bk,
    const float* __restrict__ wv, const float* __restrict__ bv,
    short* __restrict__ Q, short* __restrict__ KV,
    const float* __restrict__ pw, short* __restrict__ pwb) {
  const int tid = threadIdx.x;
  if (blockIdx.x >= 512) {
    int i = ((blockIdx.x - 512) * 256 + tid) * 4;
    float4 f = *(const float4*)(pw + i);
    bf16x4 o;
    o[0] = f2bf(f.x); o[1] = f2bf(f.y); o[2] = f2bf(f.z); o[3] = f2bf(f.w);
    *(bf16x4*)(pwb + i) = o;
    return;
  }
  __shared__ short Xs[64][136];   // 64 tokens x 128 cols (2 heads)
  __shared__ short Ws[192][72];   // Wq|Wk|Wv rows
  __shared__ short Qt[64][68], Kt[64][68], Vt[64][68];

  const int bid = blockIdx.x;
  const int tb = bid >> 3, hg = bid & 7;   // token block, head group (2 heads)
  const int s0 = (tb * 64) & (S_ - 1);
  const int kt = s0 >> 6;                  // this token block's key-tile index
  const int bb = (tb * 64) >> 11;          // batch index
  const int wave = tid >> 6, lane = tid & 63;
  const int lrow = lane & 15, quad = lane >> 4;

#pragma unroll
  for (int i = 0; i < 8; i++) {
    int c = tid + 256 * i;
    int row = c >> 5, col4 = c & 31;
    float4 f = *(const float4*)(x + ((long)(tb * 64 + row)) * E_ + hg * 128 + col4 * 4);
    bf16x4 o;
    o[0] = f2bf(f.x); o[1] = f2bf(f.y); o[2] = f2bf(f.z); o[3] = f2bf(f.w);
    *(bf16x4*)&Xs[row][col4 * 4] = o;
  }
#pragma unroll
  for (int m = 0; m < 3; m++) {
    const float* w = (m == 0) ? wq : (m == 1) ? wk : wv;
#pragma unroll
    for (int i = 0; i < 4; i++) {
      int c = tid + 256 * i;
      int row = m * 64 + (c >> 4), col = (c & 15) * 4;
      float4 f = *(const float4*)(w + (long)c * 4);
      bf16x4 o;
      o[0] = f2bf(f.x); o[1] = f2bf(f.y); o[2] = f2bf(f.z); o[3] = f2bf(f.w);
      *(bf16x4*)&Ws[row][col] = o;
    }
  }
  float bias[12];
#pragma unroll
  for (int nb = 0; nb < 12; nb++) {
    int sel = nb >> 2;
    int e = ((nb & 3) * 16) + lrow;
    bias[nb] = ((sel == 0) ? bq : (sel == 1) ? bk : bv)[e];
  }
  __syncthreads();

  bf16x8 bf0[12], bf1[12];
#pragma unroll
  for (int nb = 0; nb < 12; nb++) {
    bf0[nb] = *(bf16x8*)&Ws[nb * 16 + lrow][quad * 8];
    bf1[nb] = *(bf16x8*)&Ws[nb * 16 + lrow][32 + quad * 8];
  }

  const float QSCALE = 0.125f * 1.44269504089f;  // 1/sqrt(64) * log2(e)
  for (int hl = 0; hl < 2; hl++) {
    const int h = hg * 2 + hl;
    bf16x8 a0 = *(bf16x8*)&Xs[wave * 16 + lrow][hl * 64 + quad * 8];
    bf16x8 a1 = *(bf16x8*)&Xs[wave * 16 + lrow][hl * 64 + 32 + quad * 8];
#pragma unroll
    for (int nb = 0; nb < 12; nb++) {
      f32x4 acc = {0.f, 0.f, 0.f, 0.f};
      acc = __builtin_amdgcn_mfma_f32_16x16x32_bf16(a0, bf0[nb], acc, 0, 0, 0);
      acc = __builtin_amdgcn_mfma_f32_16x16x32_bf16(a1, bf1[nb], acc, 0, 0, 0);
      const int sel = nb >> 2;
      const float scale = (sel == 0) ? QSCALE : 1.0f;
      short (*ct)[68] = (sel == 0) ? Qt : (sel == 1) ? Kt : Vt;
#pragma unroll
      for (int r = 0; r < 4; r++) {
        ct[wave * 16 + quad * 4 + r][(nb & 3) * 16 + lrow] =
            f2bf((acc[r] + bias[nb]) * scale);
      }
    }
    __syncthreads();

    const int bh = bb * H_ + h;
    short* Qg = Q + ((long)bh * S_ + s0) * HD_;
    short* Tg = KV + ((long)(bh * 32 + kt)) * 8192;
#pragma unroll
    for (int i = 0; i < 2; i++) {
      int c = tid + 256 * i;
      int row = c >> 3, col = (c & 7) * 8;
      *(bf16x8*)(Qg + (long)row * HD_ + col) = *(bf16x8*)&Qt[row][col];
    }
#pragma unroll
    for (int u = 0; u < 4; u++) {
      int fid = tid + 256 * u;
      bf16x8 val;
      int lane2 = fid & 63;
      int quad2 = lane2 >> 4, lrow2 = lane2 & 15;
      if (u < 2) {  // K chunk
        int g = fid >> 6;
        int nb = g >> 1, half = g & 1;
        val = *(bf16x8*)&Kt[nb * 16 + lrow2][half * 32 + quad2 * 8];
      } else {      // V chunk (transpose gather)
        int g = (fid >> 6) & 7;
        int p2 = g >> 2, db = g & 3;
#pragma unroll
        for (int j = 0; j < 8; j++) {
          int key = (2 * p2 + (j >> 2)) * 16 + quad2 * 4 + (j & 3);
          val[j] = Vt[key][db * 16 + lrow2];
        }
      }
      *(bf16x8*)(Tg + fid * 8) = val;
    }
    __syncthreads();
  }
}

// ---------------------------------------------------------------- kernel 3
// Flash attention, causal, no-max (bounded scores), exp2-domain Q.
// Uniform-work decomposition: block `a` (0..15) owns strips A = a (tiles
// 0..a) and B = 31-a (tiles 0..31-a); 33 substrip-tiles per block, uniform.
// 128-key super-tiles staged via async global_load_lds into a double buffer;
// ONE barrier per 128 keys. T5: s_setprio(1) around MFMA clusters.
__global__ __launch_bounds__(256, 2) void attn_kernel(
    const short* __restrict__ Q, const short* __restrict__ KV,
    short* __restrict__ O /* [T][E] bf16 */) {
  __shared__ __align__(16) short L[2][16384];  // [buf][tile0 K|V, tile1 K|V]

  const int tid = threadIdx.x;
  const int bid = blockIdx.x;      // 512 = 16 a * 32 bh
  const int bh = bid & 31;
  const int a = bid >> 5;          // 0..15; uniform 33 units of work
  const int b = bh >> 4, h = bh & 15;
  const long qbase = ((long)bh) << 17;  // bh * S*HD

  const int wave = tid >> 6, lane = tid & 63;
  const int lrow = lane & 15, quad = lane >> 4;
  const int qgA = a * 64 + wave * 16 + lrow;          // substrip A row
  const int qgB = (31 - a) * 64 + wave * 16 + lrow;   // substrip B row
  const int tmax = 31 - a;                            // last key-tile (B diag)

  const short* qpA = Q + qbase + (long)qgA * HD_;
  const short* qpB = Q + qbase + (long)qgB * HD_;
  bf16x8 qfA0 = *(const bf16x8*)(qpA + quad * 8);
  bf16x8 qfA1 = *(const bf16x8*)(qpA + 32 + quad * 8);
  bf16x8 qfB0 = *(const bf16x8*)(qpB + quad * 8);
  bf16x8 qfB1 = *(const bf16x8*)(qpB + 32 + quad * 8);

  const char* Tg = (const char*)(KV + ((long)bh * 32) * 8192);

  // async stage one 32 KB super-tile; wave covers chunks u*4+wave (1 KB each)
  auto STAGE = [&](int sup, int buf) {
    const char* gt = Tg + (long)sup * 32768;
#pragma unroll
    for (int u = 0; u < 8; u++) {
      const int chunk = u * 4 + wave;
      gll16(gt + chunk * 1024 + lane * 16, &L[buf][chunk * 512]);
    }
  };

  // exp2 + lsum + truncate-pack one 4-fragment score set into 2 bf16x8 P^T
  // fragments whose slot->key order matches vf's (j<4: keys 32p2+quad*4+j,
  // j>=4: +16).
  auto EXPPACK = [&](f32x4* sc, bf16x8* pf, float& ls) {
#pragma unroll
    for (int p2 = 0; p2 < 2; p2++) {
      unsigned ub[8];
#pragma unroll
      for (int nb2 = 0; nb2 < 2; nb2++) {
#pragma unroll
        for (int r = 0; r < 4; r++) {
          float p = __builtin_amdgcn_exp2f(sc[2 * p2 + nb2][r]);
          ls += p;
          ub[nb2 * 4 + r] = __float_as_uint(p);
        }
      }
      union { unsigned q[4]; bf16x8 v; } pk;
      pk.q[0] = __builtin_amdgcn_perm(ub[1], ub[0], 0x07060302u);
      pk.q[1] = __builtin_amdgcn_perm(ub[3], ub[2], 0x07060302u);
      pk.q[2] = __builtin_amdgcn_perm(ub[5], ub[4], 0x07060302u);
      pk.q[3] = __builtin_amdgcn_perm(ub[7], ub[6], 0x07060302u);
      pf[p2] = pk.v;
    }
  };

  f32x4 OA[4], OB[4];
#pragma unroll
  for (int db = 0; db < 4; db++) {
    OA[db] = f32x4{0.f, 0.f, 0.f, 0.f};
    OB[db] = f32x4{0.f, 0.f, 0.f, 0.f};
  }
  float lsA = 0.f, lsB = 0.f;

  const int nsup = (33 - a) >> 1;  // supers cover tiles 0..tmax (+1 dead if a odd)
  STAGE(0, 0);
  for (int it = 0; it < nsup; it++) {
    const int buf = it & 1;
    __syncthreads();  // vmcnt drain: staging of buf complete; buf^1 free
    if (it + 1 < nsup) STAGE(it + 1, buf ^ 1);

#pragma unroll
    for (int s2 = 0; s2 < 2; s2++) {
      const int t = 2 * it + s2;     // key-tile index (keys t*64..t*64+63)
      if (t > tmax) continue;        // dead half-super (a odd), uniform branch
      const short* Lb = &L[buf][s2 * 8192];
      const bool doA = (t <= a);     // A inactive beyond its diagonal

      // K fragments (conflict-free b128), shared by substrips A and B
      bf16x8 kf[8];
#pragma unroll
      for (int g2 = 0; g2 < 8; g2++)
        kf[g2] = *(bf16x8*)&Lb[g2 * 512 + lane * 8];

      // S^T = K . Q^T
      f32x4 scA[4], scB[4];
      __builtin_amdgcn_s_setprio(1);
#pragma unroll
      for (int nb = 0; nb < 4; nb++) {
        f32x4 cb = {0.f, 0.f, 0.f, 0.f};
        cb = __builtin_amdgcn_mfma_f32_16x16x32_bf16(kf[2 * nb], qfB0, cb, 0, 0, 0);
        cb = __builtin_amdgcn_mfma_f32_16x16x32_bf16(kf[2 * nb + 1], qfB1, cb, 0, 0, 0);
        scB[nb] = cb;
      }
      if (doA) {
#pragma unroll
        for (int nb = 0; nb < 4; nb++) {
          f32x4 ca = {0.f, 0.f, 0.f, 0.f};
          ca = __builtin_amdgcn_mfma_f32_16x16x32_bf16(kf[2 * nb], qfA0, ca, 0, 0, 0);
          ca = __builtin_amdgcn_mfma_f32_16x16x32_bf16(kf[2 * nb + 1], qfA1, ca, 0, 0, 0);
          scA[nb] = ca;
        }
      }
      __builtin_amdgcn_s_setprio(0);

      // V fragments issued now; consumed after exp
      bf16x8 vf[8];
#pragma unroll
      for (int g2 = 0; g2 < 8; g2++)
        vf[g2] = *(bf16x8*)&Lb[4096 + g2 * 512 + lane * 8];

      // causal masks: A diagonal at t == a; B diagonal at t == tmax
      if (t == a) {
        const int k0 = t * 64;
#pragma unroll
        for (int nb = 0; nb < 4; nb++) {
          int kgl = k0 + nb * 16 + quad * 4;
#pragma unroll
          for (int r = 0; r < 4; r++)
            if (kgl + r > qgA) scA[nb][r] = -1e30f;
        }
      }
      if (t == tmax) {
        const int k0 = t * 64;
#pragma unroll
        for (int nb = 0; nb < 4; nb++) {
          int kgl = k0 + nb * 16 + quad * 4;
#pragma unroll
          for (int r = 0; r < 4; r++)
            if (kgl + r > qgB) scB[nb][r] = -1e30f;
        }
      }

      bf16x8 pfA8[2], pfB8[2];
      EXPPACK(scB, pfB8, lsB);
      if (doA) EXPPACK(scA, pfA8, lsA);

      // O^T += V^T . P^T, native K=32 MFMA; vf shared by both substrips
      __builtin_amdgcn_s_setprio(1);
#pragma unroll
      for (int p2 = 0; p2 < 2; p2++) {
#pragma unroll
        for (int db = 0; db < 4; db++) {
          bf16x8 vv = vf[p2 * 4 + db];
          OB[db] = __builtin_amdgcn_mfma_f32_16x16x32_bf16(vv, pfB8[p2], OB[db], 0, 0, 0);
          if (doA) {
            OA[db] = __builtin_amdgcn_mfma_f32_16x16x32_bf16(vv, pfA8[p2], OA[db], 0, 0, 0);
          }
        }
      }
      __builtin_amdgcn_s_setprio(0);
    }
  }

  // epilogue: reduce l across quads, scale, store both substrips
  lsA += __shfl_xor(lsA, 16);
  lsA += __shfl_xor(lsA, 32);
  lsB += __shfl_xor(lsB, 16);
  lsB += __shfl_xor(lsB, 32);
  const float invA = 1.f / lsA, invB = 1.f / lsB;
  short* oA = O + ((long)b * S_ + qgA) * E_ + h * HD_;
  short* oB = O + ((long)b * S_ + qgB) * E_ + h * HD_;
#pragma unroll
  for (int db = 0; db < 4; db++) {
    bf16x4 oa, ob;
#pragma unroll
    for (int r = 0; r < 4; r++) {
      oa[r] = f2bf(OA[db][r] * invA);
      ob[r] = f2bf(OB[db][r] * invB);
    }
    *(bf16x4*)(oA + db * 16 + quad * 4) = oa;
    *(bf16x4*)(oB + db * 16 + quad * 4) = ob;
  }
}

// ---------------------------------------------------------------- kernel 4
// out = attn(4096x1024 bf16) . proj_w^T + proj_b  -> fp32
// 128x64 tile (M x N), BK=64, grid 512 (2 blocks/CU).
// m97 structure: async global_load_lds (width 16) into LINEAR double-buffered
// LDS, ONE barrier per 64-deep K-step. XOR-swizzle (c^(row&7)) applied to the
// per-lane global source and the LDS read (T2/m173 pattern).
__global__ __launch_bounds__(256) void proj_kernel(
    const short* __restrict__ A, const short* __restrict__ W,
    const float* __restrict__ bias, float* __restrict__ out) {
  __shared__ __align__(16) short As[2][128][64];  // 2 x 16 KB
  __shared__ __align__(16) short Bs[2][64][64];   // 2 x  8 KB
  const int tid = threadIdx.x;
  const int bid = blockIdx.x;  // 512 = 32 (M/128) * 16 (N/64)
  const int m0 = (bid >> 4) * 128;
  const int n0 = (bid & 15) * 64;
  const int wave = tid >> 6, lane = tid & 63;
  const int wm = wave >> 1, wn = wave & 1;
  const int lrow = lane & 15, quad = lane >> 4;

  // stage one K-step: A tile 128x64 (1024 chunks), W tile 64x64 (512 chunks)
  auto STAGE = [&](int k0, int bufi) {
#pragma unroll
    for (int u = 0; u < 4; u++) {
      int d = u * 256 + tid;           // dest chunk (lane-linear)
      int row = d >> 3, c = d & 7;
      gll16(A + (long)(m0 + row) * E_ + k0 + ((c ^ (row & 7)) * 8),
            (short*)As[bufi] + (u * 256 + wave * 64) * 8);
    }
#pragma unroll
    for (int u = 0; u < 2; u++) {
      int d = u * 256 + tid;
      int row = d >> 3, c = d & 7;
      gll16(W + (long)(n0 + row) * E_ + k0 + ((c ^ (row & 7)) * 8),
            (short*)Bs[bufi] + (u * 256 + wave * 64) * 8);
    }
  };

  f32x4 acc[4][2];
#pragma unroll
  for (int i = 0; i < 4; i++)
#pragma unroll
    for (int j = 0; j < 2; j++) acc[i][j] = f32x4{0.f, 0.f, 0.f, 0.f};

  STAGE(0, 0);
  for (int kk = 0; kk < 16; kk++) {
    const int buf = kk & 1;
    __syncthreads();  // staging of buf landed; all reads of buf^1 done
    if (kk < 15) STAGE((kk + 1) * 64, buf ^ 1);

#pragma unroll
    for (int kh = 0; kh < 2; kh++) {
      bf16x8 af[4], bfr[2];
#pragma unroll
      for (int i = 0; i < 4; i++) {
        int ra = wm * 64 + i * 16 + lrow;
        af[i] = *(bf16x8*)&As[buf][ra][((kh * 4 + quad) ^ (lrow & 7)) * 8];
      }
#pragma unroll
      for (int j = 0; j < 2; j++) {
        int rb = wn * 32 + j * 16 + lrow;
        bfr[j] = *(bf16x8*)&Bs[buf][rb][((kh * 4 + quad) ^ (lrow & 7)) * 8];
      }
#pragma unroll
      for (int i = 0; i < 4; i++)
#pragma unroll
        for (int j = 0; j < 2; j++)
          acc[i][j] = __builtin_amdgcn_mfma_f32_16x16x32_bf16(af[i], bfr[j], acc[i][j], 0, 0, 0);
    }
  }

#pragma unroll
  for (int j = 0; j < 2; j++) {
    int col = n0 + wn * 32 + j * 16 + lrow;
    float bv = bias[col];
#pragma unroll
    for (int i = 0; i < 4; i++) {
#pragma unroll
      for (int r = 0; r < 4; r++) {
        int row = m0 + wm * 64 + i * 16 + quad * 4 + r;
        out[(long)row * E_ + col] = acc[i][j][r] + bv;
      }
    }
  }
}

// ---------------------------------------------------------------- launch
extern "C" void kernel_launch(void* const* d_in, const int* in_sizes, int n_in,
                              void* d_out, int out_size, void* d_ws, size_t ws_size,
                              hipStream_t stream) {
  const float* x  = (const float*)d_in[0];
  const float* wq = (const float*)d_in[1];
  const float* bq = (const float*)d_in[2];
  const float* wk = (const float*)d_in[3];
  const float* bk = (const float*)d_in[4];
  const float* wv = (const float*)d_in[5];
  const float* bv = (const float*)d_in[6];
  const float* pw = (const float*)d_in[7];
  const float* pb = (const float*)d_in[8];
  float* out = (float*)d_out;

  char* ws = (char*)d_ws;
  short* Qb = (short*)(ws);                                   // 8 MB
  short* KVb = (short*)(ws + (size_t)8 * 1024 * 1024);        // 16 MB blob
  short* AO = (short*)(ws + (size_t)24 * 1024 * 1024);        // [T][E] bf16, 8 MB
  short* PW = (short*)(ws + (size_t)32 * 1024 * 1024);        // 2 MB

  qkv_conv_kernel<<<dim3(512 + 1024), dim3(256), 0, stream>>>(
      x, wq, bq, wk, bk, wv, bv, Qb, KVb, pw, PW);
  attn_kernel<<<dim3(16 * 32), dim3(256), 0, stream>>>(Qb, KVb, AO);
  proj_kernel<<<dim3(32 * 16), dim3(256), 0, stream>>>(AO, PW, pb, out);
}